// Round 1
// baseline (1153.268 us; speedup 1.0000x reference)
//
#include <hip/hip_runtime.h>
#include <hip/hip_bf16.h>
#include <math.h>

#define HD 128

__device__ __forceinline__ float lrelu(float v) { return v > 0.0f ? v : 0.1f * v; }

// ---------------- embedding layer 1 (tiny K) ----------------
template<int IN>
__global__ __launch_bounds__(256)
void embed1_kernel(const float* __restrict__ x, const float* __restrict__ W1,
                   const float* __restrict__ b1, float* __restrict__ h1, int n) {
  int node = blockIdx.x * 2 + (threadIdx.x >> 7);
  if (node >= n) return;
  int j = threadIdx.x & 127;
  float acc = b1[j];
  #pragma unroll
  for (int k = 0; k < IN; k++) acc += x[(size_t)node * IN + k] * W1[k * HD + j];
  h1[(size_t)node * HD + j] = lrelu(acc);
}

// ---------------- fused linear: out = lrelu(A@WA [+ B@WB] + bias) ----------------
// Tile: 32 rows x 128 cols per block (256 threads). Node tile staged transposed
// in LDS (stride 36 to keep 16B-aligned, conflict-free b128 reads).
__global__ __launch_bounds__(256)
void fused_lin_kernel(const float* __restrict__ A, const float* __restrict__ WA,
                      const float* __restrict__ B, const float* __restrict__ WB,
                      const float* __restrict__ bias, float* __restrict__ out, int n_rows) {
  __shared__ __align__(16) float T[256][36];
  const int t = threadIdx.x;
  const int row0 = blockIdx.x * 32;
  const bool useB = (B != nullptr);
  {
    const int r = t >> 3;       // 0..31 row in tile
    const int c0 = t & 7;       // float4 chunk base
    const int node = row0 + r;
    #pragma unroll
    for (int i = 0; i < 4; i++) {
      const int c = c0 + 8 * i; // 0..31
      float4 v = make_float4(0.f, 0.f, 0.f, 0.f);
      if (node < n_rows) v = *(const float4*)(A + (size_t)node * HD + 4 * c);
      T[4*c+0][r] = v.x; T[4*c+1][r] = v.y; T[4*c+2][r] = v.z; T[4*c+3][r] = v.w;
    }
    if (useB) {
      #pragma unroll
      for (int i = 0; i < 4; i++) {
        const int c = c0 + 8 * i;
        float4 v = make_float4(0.f, 0.f, 0.f, 0.f);
        if (node < n_rows) v = *(const float4*)(B + (size_t)node * HD + 4 * c);
        T[128+4*c+0][r] = v.x; T[128+4*c+1][r] = v.y; T[128+4*c+2][r] = v.z; T[128+4*c+3][r] = v.w;
      }
    }
  }
  __syncthreads();
  const int ng = t & 7;   // nodes 4*ng .. 4*ng+3
  const int jg = t >> 3;  // cols 4*jg .. 4*jg+3
  const float4 bb = *(const float4*)(bias + 4 * jg);
  float acc[4][4];
  #pragma unroll
  for (int nn = 0; nn < 4; nn++) { acc[nn][0] = bb.x; acc[nn][1] = bb.y; acc[nn][2] = bb.z; acc[nn][3] = bb.w; }

  #pragma unroll 8
  for (int k = 0; k < HD; k++) {
    const float4 w = *(const float4*)(WA + (size_t)k * HD + 4 * jg);
    const float4 a = *(const float4*)(&T[k][4 * ng]);
    const float av[4] = {a.x, a.y, a.z, a.w};
    const float wv[4] = {w.x, w.y, w.z, w.w};
    #pragma unroll
    for (int nn = 0; nn < 4; nn++)
      #pragma unroll
      for (int q = 0; q < 4; q++)
        acc[nn][q] += av[nn] * wv[q];
  }
  if (useB) {
    #pragma unroll 8
    for (int k = 0; k < HD; k++) {
      const float4 w = *(const float4*)(WB + (size_t)k * HD + 4 * jg);
      const float4 a = *(const float4*)(&T[128 + k][4 * ng]);
      const float av[4] = {a.x, a.y, a.z, a.w};
      const float wv[4] = {w.x, w.y, w.z, w.w};
      #pragma unroll
      for (int nn = 0; nn < 4; nn++)
        #pragma unroll
        for (int q = 0; q < 4; q++)
          acc[nn][q] += av[nn] * wv[q];
    }
  }
  #pragma unroll
  for (int nn = 0; nn < 4; nn++) {
    const int node = row0 + 4 * ng + nn;
    if (node < n_rows) {
      float4 o;
      o.x = lrelu(acc[nn][0]); o.y = lrelu(acc[nn][1]);
      o.z = lrelu(acc[nn][2]); o.w = lrelu(acc[nn][3]);
      *(float4*)(out + (size_t)node * HD + 4 * jg) = o;
    }
  }
}

// ---------------- gather by object_ptv ----------------
__global__ __launch_bounds__(256)
void gather_kernel(const float4* __restrict__ in, const int* __restrict__ ptv,
                   float4* __restrict__ out, int n) {
  int idx = blockIdx.x * 256 + threadIdx.x;
  if (idx >= n * 32) return;
  int node = idx >> 5, c = idx & 31;
  out[idx] = in[(size_t)ptv[node] * 32 + c];
}

// ---------------- CSR build ----------------
__global__ __launch_bounds__(256)
void deg_count_kernel(const int* __restrict__ dst, int* __restrict__ deg, int nE) {
  for (int e = blockIdx.x * 256 + threadIdx.x; e < nE; e += gridDim.x * 256)
    atomicAdd(&deg[dst[e]], 1);
}

__device__ __forceinline__ int wave_incl_scan(int v) {
  int lane = threadIdx.x & 63;
  #pragma unroll
  for (int d = 1; d < 64; d <<= 1) {
    int tv = __shfl_up(v, d, 64);
    if (lane >= d) v += tv;
  }
  return v;
}

__global__ __launch_bounds__(256)
void scan1_kernel(const int* __restrict__ deg, int* __restrict__ blockSums, int n) {
  int i = blockIdx.x * 256 + threadIdx.x;
  int v = (i < n) ? deg[i] : 0;
  #pragma unroll
  for (int d = 32; d > 0; d >>= 1) v += __shfl_down(v, d, 64);
  __shared__ int ws_[4];
  if ((threadIdx.x & 63) == 0) ws_[threadIdx.x >> 6] = v;
  __syncthreads();
  if (threadIdx.x == 0) blockSums[blockIdx.x] = ws_[0] + ws_[1] + ws_[2] + ws_[3];
}

__global__ __launch_bounds__(512)
void scan2_kernel(int* __restrict__ blockSums, int nb) {
  __shared__ int buf[512];
  int t = threadIdx.x;
  int v = (t < nb) ? blockSums[t] : 0;
  buf[t] = v;
  __syncthreads();
  #pragma unroll
  for (int d = 1; d < 512; d <<= 1) {
    int x = (t >= d) ? buf[t - d] : 0;
    __syncthreads();
    buf[t] += x;
    __syncthreads();
  }
  if (t < nb) blockSums[t] = buf[t] - v;  // exclusive
}

__global__ __launch_bounds__(256)
void scan3_kernel(const int* __restrict__ deg, const int* __restrict__ blockOffs,
                  int* __restrict__ offs, float* __restrict__ inv_deg, int n) {
  int i = blockIdx.x * 256 + threadIdx.x;
  int v = (i < n) ? deg[i] : 0;
  int s = wave_incl_scan(v);
  __shared__ int ws_[4];
  int wid = threadIdx.x >> 6;
  if ((threadIdx.x & 63) == 63) ws_[wid] = s;
  __syncthreads();
  int add = blockOffs[blockIdx.x];
  for (int w = 0; w < wid; w++) add += ws_[w];
  if (i < n) {
    offs[i] = add + s - v;  // exclusive prefix
    inv_deg[i] = 1.0f / fmaxf((float)v, 1.0f);
  }
}

__global__ __launch_bounds__(256)
void csr_fill_kernel(const int* __restrict__ src, const int* __restrict__ dst,
                     const int* __restrict__ offs, int* __restrict__ cursor,
                     int* __restrict__ csr, int nE) {
  for (int e = blockIdx.x * 256 + threadIdx.x; e < nE; e += gridDim.x * 256) {
    int d = dst[e];
    int p = atomicAdd(&cursor[d], 1);
    csr[offs[d] + p] = src[e];
  }
}

// ---------------- mean aggregation over CSR ----------------
__global__ __launch_bounds__(256)
void agg_kernel(const float* __restrict__ x, const int* __restrict__ csr,
                const int* __restrict__ offs, const int* __restrict__ deg,
                const float* __restrict__ inv_deg, float* __restrict__ agg, int n) {
  int node = blockIdx.x * 8 + (threadIdx.x >> 5);
  if (node >= n) return;
  int j = threadIdx.x & 31;
  int s0 = offs[node];
  int s1 = s0 + deg[node];
  float4 acc = make_float4(0.f, 0.f, 0.f, 0.f);
  for (int e = s0; e < s1; e++) {
    int s = csr[e];
    float4 v = *(const float4*)(x + (size_t)s * HD + 4 * j);
    acc.x += v.x; acc.y += v.y; acc.z += v.z; acc.w += v.w;
  }
  float id = inv_deg[node];
  float4 o = make_float4(acc.x * id, acc.y * id, acc.z * id, acc.w * id);
  *(float4*)(agg + (size_t)node * HD + 4 * j) = o;
}

// ---------------- output layer ----------------
__global__ __launch_bounds__(256)
void out_kernel(const float* __restrict__ agg, const float* __restrict__ x,
                const float* __restrict__ Wl, const float* __restrict__ bl,
                const float* __restrict__ Wr, float* __restrict__ out, int n) {
  int node = blockIdx.x * 4 + (threadIdx.x >> 6);
  if (node >= n) return;
  int lane = threadIdx.x & 63;
  const float2 a  = *(const float2*)(agg + (size_t)node * HD + 2 * lane);
  const float2 xv = *(const float2*)(x   + (size_t)node * HD + 2 * lane);
  const float2 wl = *(const float2*)(Wl + 2 * lane);
  const float2 wr = *(const float2*)(Wr + 2 * lane);
  float s = a.x * wl.x + a.y * wl.y + xv.x * wr.x + xv.y * wr.y;
  #pragma unroll
  for (int d = 32; d > 0; d >>= 1) s += __shfl_down(s, d, 64);
  if (lane == 0) out[node] = 1.0f / (1.0f + expf(-(s + bl[0])));
}

extern "C" void kernel_launch(void* const* d_in, const int* in_sizes, int n_in,
                              void* d_out, int out_size, void* d_ws, size_t ws_size,
                              hipStream_t stream) {
  const float* x_gen  = (const float*)d_in[0];
  const float* x_load = (const float*)d_in[1];
  const float* x_or   = (const float*)d_in[2];
  const float* x_ex   = (const float*)d_in[3];
  const int*   edge   = (const int*)d_in[4];
  const int*   ptv    = (const int*)d_in[5];
  const float* Wg1  = (const float*)d_in[6],  *bg1  = (const float*)d_in[7];
  const float* Wg2  = (const float*)d_in[8],  *bg2  = (const float*)d_in[9];
  const float* Wld1 = (const float*)d_in[10], *bld1 = (const float*)d_in[11];
  const float* Wld2 = (const float*)d_in[12], *bld2 = (const float*)d_in[13];
  const float* Wor1 = (const float*)d_in[14], *bor1 = (const float*)d_in[15];
  const float* Wor2 = (const float*)d_in[16], *bor2 = (const float*)d_in[17];
  const float* Wex1 = (const float*)d_in[18], *bex1 = (const float*)d_in[19];
  const float* Wex2 = (const float*)d_in[20], *bex2 = (const float*)d_in[21];
  const float* Wl_h = (const float*)d_in[22], *bl_h = (const float*)d_in[23];
  const float* Wr_h = (const float*)d_in[24];
  const float* Wl_o = (const float*)d_in[25], *bl_o = (const float*)d_in[26];
  const float* Wr_o = (const float*)d_in[27];

  const int n_gen  = in_sizes[0] / 3;
  const int n_load = in_sizes[1] / 3;
  const int n_or   = in_sizes[2] / 6;
  const int n_ex   = in_sizes[3] / 6;
  const int nE     = in_sizes[4] / 2;
  const int N      = in_sizes[5];
  const int* esrc = edge;
  const int* edst = edge + nE;

  // workspace layout
  float* bufA = (float*)d_ws;
  float* bufB = bufA + (size_t)N * HD;
  float* bufC = bufB + (size_t)N * HD;
  int*   deg     = (int*)(bufC + (size_t)N * HD);
  int*   offs    = deg + N;
  int*   cursor  = offs + N;
  float* inv_deg = (float*)(cursor + N);
  int*   blockSums = (int*)(inv_deg + N);
  int*   csr     = blockSums + 1024;

  hipMemsetAsync(deg, 0, (size_t)N * sizeof(int), stream);
  hipMemsetAsync(cursor, 0, (size_t)N * sizeof(int), stream);

  // --- embeddings, layer 1 -> bufB ---
  embed1_kernel<3><<<(n_gen  + 1) / 2, 256, 0, stream>>>(x_gen,  Wg1,  bg1,  bufB, n_gen);
  embed1_kernel<3><<<(n_load + 1) / 2, 256, 0, stream>>>(x_load, Wld1, bld1, bufB + (size_t)n_gen * HD, n_load);
  embed1_kernel<6><<<(n_or   + 1) / 2, 256, 0, stream>>>(x_or,   Wor1, bor1, bufB + (size_t)(n_gen + n_load) * HD, n_or);
  embed1_kernel<6><<<(n_ex   + 1) / 2, 256, 0, stream>>>(x_ex,   Wex1, bex1, bufB + (size_t)(n_gen + n_load + n_or) * HD, n_ex);

  // --- embeddings, layer 2 -> bufC ---
  size_t o0 = 0, o1 = (size_t)n_gen * HD, o2 = (size_t)(n_gen + n_load) * HD, o3 = (size_t)(n_gen + n_load + n_or) * HD;
  fused_lin_kernel<<<(n_gen  + 31) / 32, 256, 0, stream>>>(bufB + o0, Wg2,  nullptr, nullptr, bg2,  bufC + o0, n_gen);
  fused_lin_kernel<<<(n_load + 31) / 32, 256, 0, stream>>>(bufB + o1, Wld2, nullptr, nullptr, bld2, bufC + o1, n_load);
  fused_lin_kernel<<<(n_or   + 31) / 32, 256, 0, stream>>>(bufB + o2, Wor2, nullptr, nullptr, bor2, bufC + o2, n_or);
  fused_lin_kernel<<<(n_ex   + 31) / 32, 256, 0, stream>>>(bufB + o3, Wex2, nullptr, nullptr, bex2, bufC + o3, n_ex);

  // --- gather by object_ptv: bufC -> bufA ---
  gather_kernel<<<(N * 32 + 255) / 256, 256, 0, stream>>>((const float4*)bufC, ptv, (float4*)bufA, N);

  // --- CSR build ---
  const int nb = (N + 255) / 256;
  deg_count_kernel<<<1024, 256, 0, stream>>>(edst, deg, nE);
  scan1_kernel<<<nb, 256, 0, stream>>>(deg, blockSums, N);
  scan2_kernel<<<1, 512, 0, stream>>>(blockSums, nb);
  scan3_kernel<<<nb, 256, 0, stream>>>(deg, blockSums, offs, inv_deg, N);
  csr_fill_kernel<<<1024, 256, 0, stream>>>(esrc, edst, offs, cursor, csr, nE);

  // --- hidden SAGE layers ---
  float* xcur = bufA;
  float* xnext = bufC;
  for (int l = 0; l < 3; l++) {
    agg_kernel<<<(N + 7) / 8, 256, 0, stream>>>(xcur, csr, offs, deg, inv_deg, bufB, N);
    fused_lin_kernel<<<(N + 31) / 32, 256, 0, stream>>>(bufB, Wl_h + (size_t)l * HD * HD,
                                                        xcur, Wr_h + (size_t)l * HD * HD,
                                                        bl_h + (size_t)l * HD, xnext, N);
    float* tmp = xcur; xcur = xnext; xnext = tmp;
  }

  // --- output layer ---
  agg_kernel<<<(N + 7) / 8, 256, 0, stream>>>(xcur, csr, offs, deg, inv_deg, bufB, N);
  out_kernel<<<(N + 3) / 4, 256, 0, stream>>>(bufB, xcur, Wl_o, bl_o, Wr_o, (float*)d_out, N);
}

// Round 2
// 671.148 us; speedup vs baseline: 1.7184x; 1.7184x over previous
//
#include <hip/hip_runtime.h>
#include <hip/hip_bf16.h>
#include <math.h>

#define HD 128

typedef __attribute__((ext_vector_type(8))) short  bf16x8;
typedef __attribute__((ext_vector_type(4))) float  f32x4;
typedef __attribute__((ext_vector_type(8))) unsigned short ushort8;

__device__ __forceinline__ float lrelu(float v) { return v > 0.0f ? v : 0.1f * v; }

__device__ __forceinline__ unsigned short f2bf(float f) {
  union { float f; unsigned u; } c; c.f = f;
  unsigned u = c.u + 0x7fffu + ((c.u >> 16) & 1u);   // RNE
  return (unsigned short)(u >> 16);
}
__device__ __forceinline__ float bf2f(unsigned short u) {
  return __uint_as_float((unsigned)u << 16);
}

// ---------------- embedding layer 1 (tiny K), bf16 out ----------------
template<int IN>
__global__ __launch_bounds__(256)
void embed1_kernel(const float* __restrict__ x, const float* __restrict__ W1,
                   const float* __restrict__ b1, unsigned short* __restrict__ h1, int n) {
  int node = blockIdx.x * 2 + (threadIdx.x >> 7);
  if (node >= n) return;
  int j = threadIdx.x & 127;
  float acc = b1[j];
  #pragma unroll
  for (int k = 0; k < IN; k++) acc += x[(size_t)node * IN + k] * W1[k * HD + j];
  h1[(size_t)node * HD + j] = f2bf(lrelu(acc));
}

// ---------------- weight repack: f32 [k][j] -> bf16 packed [(k/32)][j][4][8] ----------------
// element (ks,j,g,b) = W[32*ks + 8*g + b][j];  lane l reads 16B at ((ks*128+cb*16+(l&15))*4 + (l>>4))*8
__global__ __launch_bounds__(256)
void wprep_all_kernel(const float* __restrict__ Wg2, const float* __restrict__ Wld2,
                      const float* __restrict__ Wor2, const float* __restrict__ Wex2,
                      const float* __restrict__ Wl_h, const float* __restrict__ Wr_h,
                      unsigned short* __restrict__ Wp) {
  int tid = blockIdx.x * 256 + threadIdx.x;      // 10 * 16384 total
  int m = tid >> 14;
  int i = tid & 16383;
  const float* src; unsigned short* dst;
  switch (m) {
    case 0: src = Wg2;  dst = Wp;             break;
    case 1: src = Wld2; dst = Wp + 16384;     break;
    case 2: src = Wor2; dst = Wp + 2 * 16384; break;
    case 3: src = Wex2; dst = Wp + 3 * 16384; break;
    default: {
      int mm = m - 4; int l = mm >> 1; int isR = mm & 1;
      src = (isR ? Wr_h : Wl_h) + (size_t)l * 16384;
      dst = Wp + 4 * 16384 + (size_t)l * 32768 + (isR ? 16384 : 0);
    }
  }
  int k = i >> 7, j = i & 127;
  int ks = k >> 5, g = (k >> 3) & 3, b = k & 7;
  dst[((ks * 128 + j) * 4 + g) * 8 + b] = f2bf(src[i]);
}

// ---------------- MFMA fused linear: out = lrelu(Aa@W[0:KA] (+ Ab@W[KA:KA+KB]) + bias) ----------------
// 64 rows x 128 cols per block; 4 waves, wave w -> rows [16w,16w+16), 8 col-frags of 16.
template<int KA, int KB>
__global__ __launch_bounds__(256)
void mfma_lin_kernel(const unsigned short* __restrict__ Aa, const unsigned short* __restrict__ Ab,
                     const unsigned short* __restrict__ Wp, const float* __restrict__ bias,
                     unsigned short* __restrict__ out, int n_rows) {
  const int t = threadIdx.x;
  const int w = t >> 6;
  const int l = t & 63;
  const int lr = l & 15;      // frag row (A) / frag col (B,D)
  const int lg = l >> 4;      // k-group 0..3
  const int row0 = blockIdx.x * 64 + w * 16;
  int ra = row0 + lr; if (ra >= n_rows) ra = n_rows - 1;   // clamp for safe loads

  const unsigned short* wbase = Wp + (size_t)lr * 32 + (size_t)lg * 8;
  const unsigned short* abase = Aa + (size_t)ra * HD + 8 * lg;

  f32x4 acc[8];
  #pragma unroll
  for (int cb = 0; cb < 8; cb++) {
    float bv = bias[cb * 16 + lr];
    acc[cb] = (f32x4){bv, bv, bv, bv};
  }

  #pragma unroll
  for (int ks = 0; ks < KA; ks++) {
    bf16x8 af = *(const bf16x8*)(abase + ks * 32);
    #pragma unroll
    for (int cb = 0; cb < 8; cb++) {
      bf16x8 bfv = *(const bf16x8*)(wbase + (size_t)(ks * 128 + cb * 16) * 32);
      acc[cb] = __builtin_amdgcn_mfma_f32_16x16x32_bf16(af, bfv, acc[cb], 0, 0, 0);
    }
  }
  if constexpr (KB > 0) {
    const unsigned short* bbase = Ab + (size_t)ra * HD + 8 * lg;
    #pragma unroll
    for (int ks = 0; ks < KB; ks++) {
      bf16x8 af = *(const bf16x8*)(bbase + ks * 32);
      #pragma unroll
      for (int cb = 0; cb < 8; cb++) {
        bf16x8 bfv = *(const bf16x8*)(wbase + (size_t)((KA + ks) * 128 + cb * 16) * 32);
        acc[cb] = __builtin_amdgcn_mfma_f32_16x16x32_bf16(af, bfv, acc[cb], 0, 0, 0);
      }
    }
  }

  // D: row = lg*4 + r, col = cb*16 + lr
  #pragma unroll
  for (int cb = 0; cb < 8; cb++) {
    #pragma unroll
    for (int r = 0; r < 4; r++) {
      int node = row0 + lg * 4 + r;
      if (node < n_rows)
        out[(size_t)node * HD + cb * 16 + lr] = f2bf(lrelu(acc[cb][r]));
    }
  }
}

// ---------------- gather by object_ptv (bf16 rows, 16B chunks) ----------------
__global__ __launch_bounds__(256)
void gather_kernel(const float4* __restrict__ in, const int* __restrict__ ptv,
                   float4* __restrict__ out, int n) {
  int idx = blockIdx.x * 256 + threadIdx.x;
  if (idx >= n * 16) return;
  int node = idx >> 4, c = idx & 15;
  out[idx] = in[(size_t)ptv[node] * 16 + c];
}

// ---------------- CSR build ----------------
__global__ __launch_bounds__(256)
void deg_count_kernel(const int* __restrict__ dst, int* __restrict__ deg, int nE) {
  for (int e = blockIdx.x * 256 + threadIdx.x; e < nE; e += gridDim.x * 256)
    atomicAdd(&deg[dst[e]], 1);
}

__device__ __forceinline__ int wave_incl_scan(int v) {
  int lane = threadIdx.x & 63;
  #pragma unroll
  for (int d = 1; d < 64; d <<= 1) {
    int tv = __shfl_up(v, d, 64);
    if (lane >= d) v += tv;
  }
  return v;
}

__global__ __launch_bounds__(256)
void scan1_kernel(const int* __restrict__ deg, int* __restrict__ blockSums, int n) {
  int i = blockIdx.x * 256 + threadIdx.x;
  int v = (i < n) ? deg[i] : 0;
  #pragma unroll
  for (int d = 32; d > 0; d >>= 1) v += __shfl_down(v, d, 64);
  __shared__ int ws_[4];
  if ((threadIdx.x & 63) == 0) ws_[threadIdx.x >> 6] = v;
  __syncthreads();
  if (threadIdx.x == 0) blockSums[blockIdx.x] = ws_[0] + ws_[1] + ws_[2] + ws_[3];
}

__global__ __launch_bounds__(512)
void scan2_kernel(int* __restrict__ blockSums, int nb) {
  __shared__ int buf[512];
  int t = threadIdx.x;
  int v = (t < nb) ? blockSums[t] : 0;
  buf[t] = v;
  __syncthreads();
  #pragma unroll
  for (int d = 1; d < 512; d <<= 1) {
    int x = (t >= d) ? buf[t - d] : 0;
    __syncthreads();
    buf[t] += x;
    __syncthreads();
  }
  if (t < nb) blockSums[t] = buf[t] - v;  // exclusive
}

__global__ __launch_bounds__(256)
void scan3_kernel(const int* __restrict__ deg, const int* __restrict__ blockOffs,
                  int* __restrict__ offs, float* __restrict__ inv_deg, int n) {
  int i = blockIdx.x * 256 + threadIdx.x;
  int v = (i < n) ? deg[i] : 0;
  int s = wave_incl_scan(v);
  __shared__ int ws_[4];
  int wid = threadIdx.x >> 6;
  if ((threadIdx.x & 63) == 63) ws_[wid] = s;
  __syncthreads();
  int add = blockOffs[blockIdx.x];
  for (int w = 0; w < wid; w++) add += ws_[w];
  if (i < n) {
    offs[i] = add + s - v;
    inv_deg[i] = 1.0f / fmaxf((float)v, 1.0f);
  }
}

__global__ __launch_bounds__(256)
void csr_fill_kernel(const int* __restrict__ src, const int* __restrict__ dst,
                     const int* __restrict__ offs, int* __restrict__ cursor,
                     int* __restrict__ csr, int nE) {
  for (int e = blockIdx.x * 256 + threadIdx.x; e < nE; e += gridDim.x * 256) {
    int d = dst[e];
    int p = atomicAdd(&cursor[d], 1);
    csr[offs[d] + p] = src[e];
  }
}

// ---------------- mean aggregation over CSR (bf16 in/out, f32 accum) ----------------
__global__ __launch_bounds__(256)
void agg_bf16_kernel(const unsigned short* __restrict__ x, const int* __restrict__ csr,
                     const int* __restrict__ offs, const int* __restrict__ deg,
                     const float* __restrict__ inv_deg, unsigned short* __restrict__ agg, int n) {
  int node = blockIdx.x * 16 + (threadIdx.x >> 4);
  if (node >= n) return;
  int j = threadIdx.x & 15;                  // 8-col group
  int s0 = offs[node];
  int s1 = s0 + deg[node];
  float acc[8] = {0.f, 0.f, 0.f, 0.f, 0.f, 0.f, 0.f, 0.f};
  for (int e = s0; e < s1; e++) {
    int s = csr[e];
    ushort8 v = *(const ushort8*)(x + (size_t)s * HD + 8 * j);
    #pragma unroll
    for (int q = 0; q < 8; q++) acc[q] += bf2f(v[q]);
  }
  float id = inv_deg[node];
  ushort8 o;
  #pragma unroll
  for (int q = 0; q < 8; q++) o[q] = f2bf(acc[q] * id);
  *(ushort8*)(agg + (size_t)node * HD + 8 * j) = o;
}

// ---------------- output layer ----------------
__global__ __launch_bounds__(256)
void out_kernel(const unsigned short* __restrict__ agg, const unsigned short* __restrict__ x,
                const float* __restrict__ Wl, const float* __restrict__ bl,
                const float* __restrict__ Wr, float* __restrict__ out, int n) {
  int node = blockIdx.x * 4 + (threadIdx.x >> 6);
  if (node >= n) return;
  int lane = threadIdx.x & 63;
  unsigned av = *(const unsigned*)(agg + (size_t)node * HD + 2 * lane);
  unsigned xv = *(const unsigned*)(x   + (size_t)node * HD + 2 * lane);
  const float2 wl = *(const float2*)(Wl + 2 * lane);
  const float2 wr = *(const float2*)(Wr + 2 * lane);
  float s = bf2f((unsigned short)(av & 0xffff)) * wl.x + bf2f((unsigned short)(av >> 16)) * wl.y
          + bf2f((unsigned short)(xv & 0xffff)) * wr.x + bf2f((unsigned short)(xv >> 16)) * wr.y;
  #pragma unroll
  for (int d = 32; d > 0; d >>= 1) s += __shfl_down(s, d, 64);
  if (lane == 0) out[node] = 1.0f / (1.0f + expf(-(s + bl[0])));
}

extern "C" void kernel_launch(void* const* d_in, const int* in_sizes, int n_in,
                              void* d_out, int out_size, void* d_ws, size_t ws_size,
                              hipStream_t stream) {
  const float* x_gen  = (const float*)d_in[0];
  const float* x_load = (const float*)d_in[1];
  const float* x_or   = (const float*)d_in[2];
  const float* x_ex   = (const float*)d_in[3];
  const int*   edge   = (const int*)d_in[4];
  const int*   ptv    = (const int*)d_in[5];
  const float* Wg1  = (const float*)d_in[6],  *bg1  = (const float*)d_in[7];
  const float* Wg2  = (const float*)d_in[8],  *bg2  = (const float*)d_in[9];
  const float* Wld1 = (const float*)d_in[10], *bld1 = (const float*)d_in[11];
  const float* Wld2 = (const float*)d_in[12], *bld2 = (const float*)d_in[13];
  const float* Wor1 = (const float*)d_in[14], *bor1 = (const float*)d_in[15];
  const float* Wor2 = (const float*)d_in[16], *bor2 = (const float*)d_in[17];
  const float* Wex1 = (const float*)d_in[18], *bex1 = (const float*)d_in[19];
  const float* Wex2 = (const float*)d_in[20], *bex2 = (const float*)d_in[21];
  const float* Wl_h = (const float*)d_in[22], *bl_h = (const float*)d_in[23];
  const float* Wr_h = (const float*)d_in[24];
  const float* Wl_o = (const float*)d_in[25], *bl_o = (const float*)d_in[26];
  const float* Wr_o = (const float*)d_in[27];

  const int n_gen  = in_sizes[0] / 3;
  const int n_load = in_sizes[1] / 3;
  const int n_or   = in_sizes[2] / 6;
  const int n_ex   = in_sizes[3] / 6;
  const int nE     = in_sizes[4] / 2;
  const int N      = in_sizes[5];
  const int* esrc = edge;
  const int* edst = edge + nE;

  // ---- workspace layout (bf16 activations) ----
  size_t nel = (size_t)N * HD;
  unsigned short* b0 = (unsigned short*)d_ws;   // h1 (embed layer-1 out)
  unsigned short* b1 = b0 + nel;                // x current
  unsigned short* b2 = b1 + nel;                // agg
  unsigned short* b3 = b2 + nel;                // next / tmp
  int*   deg     = (int*)(b3 + nel);
  int*   offs    = deg + N;
  int*   cursor  = offs + N;
  float* inv_deg = (float*)(cursor + N);
  int*   blockSums = (int*)(inv_deg + N);
  int*   csr     = blockSums + 1024;
  uintptr_t wp_addr = ((uintptr_t)(csr + nE) + 15) & ~(uintptr_t)15;
  unsigned short* Wp = (unsigned short*)wp_addr;       // 4*16384 embed + 3*32768 combine

  hipMemsetAsync(deg, 0, (size_t)N * sizeof(int), stream);
  hipMemsetAsync(cursor, 0, (size_t)N * sizeof(int), stream);

  // ---- weight repack (one launch) ----
  wprep_all_kernel<<<640, 256, 0, stream>>>(Wg2, Wld2, Wor2, Wex2, Wl_h, Wr_h, Wp);

  // ---- embeddings, layer 1 -> b0 ----
  size_t o0 = 0, o1 = (size_t)n_gen * HD, o2 = (size_t)(n_gen + n_load) * HD,
         o3 = (size_t)(n_gen + n_load + n_or) * HD;
  embed1_kernel<3><<<(n_gen  + 1) / 2, 256, 0, stream>>>(x_gen,  Wg1,  bg1,  b0 + o0, n_gen);
  embed1_kernel<3><<<(n_load + 1) / 2, 256, 0, stream>>>(x_load, Wld1, bld1, b0 + o1, n_load);
  embed1_kernel<6><<<(n_or   + 1) / 2, 256, 0, stream>>>(x_or,   Wor1, bor1, b0 + o2, n_or);
  embed1_kernel<6><<<(n_ex   + 1) / 2, 256, 0, stream>>>(x_ex,   Wex1, bex1, b0 + o3, n_ex);

  // ---- embeddings, layer 2 (MFMA) -> b3 ----
  mfma_lin_kernel<4,0><<<(n_gen  + 63) / 64, 256, 0, stream>>>(b0 + o0, nullptr, Wp,             bg2,  b3 + o0, n_gen);
  mfma_lin_kernel<4,0><<<(n_load + 63) / 64, 256, 0, stream>>>(b0 + o1, nullptr, Wp + 16384,     bld2, b3 + o1, n_load);
  mfma_lin_kernel<4,0><<<(n_or   + 63) / 64, 256, 0, stream>>>(b0 + o2, nullptr, Wp + 2 * 16384, bor2, b3 + o2, n_or);
  mfma_lin_kernel<4,0><<<(n_ex   + 63) / 64, 256, 0, stream>>>(b0 + o3, nullptr, Wp + 3 * 16384, bex2, b3 + o3, n_ex);

  // ---- gather by object_ptv: b3 -> b1 ----
  gather_kernel<<<(N * 16 + 255) / 256, 256, 0, stream>>>((const float4*)b3, ptv, (float4*)b1, N);

  // ---- CSR build ----
  const int nb = (N + 255) / 256;
  deg_count_kernel<<<1024, 256, 0, stream>>>(edst, deg, nE);
  scan1_kernel<<<nb, 256, 0, stream>>>(deg, blockSums, N);
  scan2_kernel<<<1, 512, 0, stream>>>(blockSums, nb);
  scan3_kernel<<<nb, 256, 0, stream>>>(deg, blockSums, offs, inv_deg, N);
  csr_fill_kernel<<<1024, 256, 0, stream>>>(esrc, edst, offs, cursor, csr, nE);

  // ---- hidden SAGE layers ----
  unsigned short* xcur = b1;
  unsigned short* xnext = b3;
  const unsigned short* WpC = Wp + 4 * 16384;
  for (int l = 0; l < 3; l++) {
    agg_bf16_kernel<<<(N + 15) / 16, 256, 0, stream>>>(xcur, csr, offs, deg, inv_deg, b2, N);
    mfma_lin_kernel<4,4><<<(N + 63) / 64, 256, 0, stream>>>(b2, xcur, WpC + (size_t)l * 32768,
                                                            bl_h + (size_t)l * HD, xnext, N);
    unsigned short* tmp = xcur; xcur = xnext; xnext = tmp;
  }

  // ---- output layer ----
  agg_bf16_kernel<<<(N + 15) / 16, 256, 0, stream>>>(xcur, csr, offs, deg, inv_deg, b2, N);
  out_kernel<<<(N + 3) / 4, 256, 0, stream>>>(b2, xcur, Wl_o, bl_o, Wr_o, (float*)d_out, N);
}

// Round 3
// 437.663 us; speedup vs baseline: 2.6351x; 1.5335x over previous
//
#include <hip/hip_runtime.h>
#include <hip/hip_bf16.h>
#include <math.h>

#define HD 128
#define NPB 512        // nodes per bucket
#define CAP 16384      // edge capacity per bucket (avg ~8163, sigma ~90 -> 2x headroom)
#define SCHUNK 4096    // edges per scatter block

typedef __attribute__((ext_vector_type(8))) short  bf16x8;
typedef __attribute__((ext_vector_type(4))) float  f32x4;
typedef __attribute__((ext_vector_type(8))) unsigned short ushort8;

__device__ __forceinline__ float lrelu(float v) { return v > 0.0f ? v : 0.1f * v; }

__device__ __forceinline__ unsigned short f2bf(float f) {
  union { float f; unsigned u; } c; c.f = f;
  unsigned u = c.u + 0x7fffu + ((c.u >> 16) & 1u);   // RNE
  return (unsigned short)(u >> 16);
}
__device__ __forceinline__ float bf2f(unsigned short u) {
  return __uint_as_float((unsigned)u << 16);
}

// ---------------- embedding layer 1 (all types, padded node ids) ----------------
__global__ __launch_bounds__(256)
void embed1_kernel(const float* __restrict__ xg, const float* __restrict__ xl,
                   const float* __restrict__ xo, const float* __restrict__ xe,
                   const float* __restrict__ Wg, const float* __restrict__ bg,
                   const float* __restrict__ Wl, const float* __restrict__ bl,
                   const float* __restrict__ Wo, const float* __restrict__ bo,
                   const float* __restrict__ We, const float* __restrict__ be,
                   unsigned short* __restrict__ h1, int4 padCum, int4 realCnt) {
  int p = blockIdx.x * 2 + (threadIdx.x >> 7);
  if (p >= padCum.w) return;
  int j = threadIdx.x & 127;
  int typ = (p < padCum.x) ? 0 : (p < padCum.y) ? 1 : (p < padCum.z) ? 2 : 3;
  int padStart = (typ == 0) ? 0 : (typ == 1) ? padCum.x : (typ == 2) ? padCum.y : padCum.z;
  int cnt = (typ == 0) ? realCnt.x : (typ == 1) ? realCnt.y : (typ == 2) ? realCnt.z : realCnt.w;
  int loc = p - padStart;
  if (loc >= cnt) return;
  const float *x, *W, *bb; int IN;
  if (typ == 0)      { x = xg; W = Wg; bb = bg; IN = 3; }
  else if (typ == 1) { x = xl; W = Wl; bb = bl; IN = 3; }
  else if (typ == 2) { x = xo; W = Wo; bb = bo; IN = 6; }
  else               { x = xe; W = We; bb = be; IN = 6; }
  float acc = bb[j];
  for (int k = 0; k < IN; k++) acc += x[(size_t)loc * IN + k] * W[k * HD + j];
  h1[(size_t)p * HD + j] = f2bf(lrelu(acc));
}

// ---------------- weight repack: f32 [k][j] -> bf16 packed [(k/32)][j][4][8] ----------------
__global__ __launch_bounds__(256)
void wprep_all_kernel(const float* __restrict__ Wg2, const float* __restrict__ Wld2,
                      const float* __restrict__ Wor2, const float* __restrict__ Wex2,
                      const float* __restrict__ Wl_h, const float* __restrict__ Wr_h,
                      unsigned short* __restrict__ Wp) {
  int tid = blockIdx.x * 256 + threadIdx.x;      // 10 * 16384 total
  int m = tid >> 14;
  int i = tid & 16383;
  const float* src; unsigned short* dst;
  switch (m) {
    case 0: src = Wg2;  dst = Wp;             break;
    case 1: src = Wld2; dst = Wp + 16384;     break;
    case 2: src = Wor2; dst = Wp + 2 * 16384; break;
    case 3: src = Wex2; dst = Wp + 3 * 16384; break;
    default: {
      int mm = m - 4; int l = mm >> 1; int isR = mm & 1;
      src = (isR ? Wr_h : Wl_h) + (size_t)l * 16384;
      dst = Wp + 4 * 16384 + (size_t)l * 32768 + (isR ? 16384 : 0);
    }
  }
  int k = i >> 7, j = i & 127;
  int ks = k >> 5, g = (k >> 3) & 3, b = k & 7;
  dst[((ks * 128 + j) * 4 + g) * 8 + b] = f2bf(src[i]);
}

// ---------------- inverse permutation of object_ptv ----------------
__global__ __launch_bounds__(256)
void invptv_kernel(const int* __restrict__ ptv, int* __restrict__ inv, int n) {
  int i = blockIdx.x * 256 + threadIdx.x;
  if (i < n) inv[ptv[i]] = i;
}

// ---------------- embedding layer 2 (MFMA, padded segments, scatter via inv) ----------------
__global__ __launch_bounds__(256)
void mfma_embed2_kernel(const unsigned short* __restrict__ h1,
                        const unsigned short* __restrict__ Wp,
                        const float* __restrict__ b_g, const float* __restrict__ b_ld,
                        const float* __restrict__ b_or, const float* __restrict__ b_ex,
                        const int* __restrict__ inv, unsigned short* __restrict__ out,
                        int4 padCum, int4 realStart, int4 realCnt) {
  const int t = threadIdx.x, w = t >> 6, l = t & 63;
  const int lr = l & 15, lg = l >> 4;
  const int prow0 = blockIdx.x * 64 + w * 16;
  int typ = (prow0 < padCum.x) ? 0 : (prow0 < padCum.y) ? 1 : (prow0 < padCum.z) ? 2 : 3;
  int padStart = (typ == 0) ? 0 : (typ == 1) ? padCum.x : (typ == 2) ? padCum.y : padCum.z;
  int rStart = (typ == 0) ? realStart.x : (typ == 1) ? realStart.y : (typ == 2) ? realStart.z : realStart.w;
  int cnt = (typ == 0) ? realCnt.x : (typ == 1) ? realCnt.y : (typ == 2) ? realCnt.z : realCnt.w;
  const float* bias = (typ == 0) ? b_g : (typ == 1) ? b_ld : (typ == 2) ? b_or : b_ex;

  int raLoc = prow0 + lr - padStart; if (raLoc >= cnt) raLoc = cnt - 1;
  const unsigned short* abase = h1 + (size_t)(padStart + raLoc) * HD + 8 * lg;
  const unsigned short* wbase = Wp + (size_t)typ * 16384 + lr * 32 + lg * 8;

  f32x4 acc[8];
  #pragma unroll
  for (int cb = 0; cb < 8; cb++) {
    float bv = bias[cb * 16 + lr];
    acc[cb] = (f32x4){bv, bv, bv, bv};
  }
  #pragma unroll
  for (int ks = 0; ks < 4; ks++) {
    bf16x8 af = *(const bf16x8*)(abase + ks * 32);
    #pragma unroll
    for (int cb = 0; cb < 8; cb++) {
      bf16x8 bfv = *(const bf16x8*)(wbase + (size_t)(ks * 128 + cb * 16) * 32);
      acc[cb] = __builtin_amdgcn_mfma_f32_16x16x32_bf16(af, bfv, acc[cb], 0, 0, 0);
    }
  }
  int tgt[4];
  #pragma unroll
  for (int r = 0; r < 4; r++) {
    int locRow = prow0 + lg * 4 + r - padStart;
    tgt[r] = (locRow < cnt) ? inv[rStart + locRow] : -1;
  }
  #pragma unroll
  for (int cb = 0; cb < 8; cb++) {
    #pragma unroll
    for (int r = 0; r < 4; r++) {
      if (tgt[r] >= 0)
        out[(size_t)tgt[r] * HD + cb * 16 + lr] = f2bf(lrelu(acc[cb][r]));
    }
  }
}

// ---------------- MFMA combine: out = lrelu(agg@Wl + x@Wr + bias) ----------------
__global__ __launch_bounds__(256)
void mfma_comb_kernel(const unsigned short* __restrict__ Aa, const unsigned short* __restrict__ Ab,
                      const unsigned short* __restrict__ Wp, const float* __restrict__ bias,
                      unsigned short* __restrict__ out, int n_rows) {
  const int t = threadIdx.x;
  const int w = t >> 6;
  const int l = t & 63;
  const int lr = l & 15;
  const int lg = l >> 4;
  const int row0 = blockIdx.x * 64 + w * 16;
  int ra = row0 + lr; if (ra >= n_rows) ra = n_rows - 1;

  const unsigned short* wbase = Wp + (size_t)lr * 32 + (size_t)lg * 8;
  const unsigned short* abase = Aa + (size_t)ra * HD + 8 * lg;
  const unsigned short* bbase = Ab + (size_t)ra * HD + 8 * lg;

  f32x4 acc[8];
  #pragma unroll
  for (int cb = 0; cb < 8; cb++) {
    float bv = bias[cb * 16 + lr];
    acc[cb] = (f32x4){bv, bv, bv, bv};
  }
  #pragma unroll
  for (int ks = 0; ks < 4; ks++) {
    bf16x8 af = *(const bf16x8*)(abase + ks * 32);
    #pragma unroll
    for (int cb = 0; cb < 8; cb++) {
      bf16x8 bfv = *(const bf16x8*)(wbase + (size_t)(ks * 128 + cb * 16) * 32);
      acc[cb] = __builtin_amdgcn_mfma_f32_16x16x32_bf16(af, bfv, acc[cb], 0, 0, 0);
    }
  }
  #pragma unroll
  for (int ks = 0; ks < 4; ks++) {
    bf16x8 af = *(const bf16x8*)(bbase + ks * 32);
    #pragma unroll
    for (int cb = 0; cb < 8; cb++) {
      bf16x8 bfv = *(const bf16x8*)(wbase + (size_t)((4 + ks) * 128 + cb * 16) * 32);
      acc[cb] = __builtin_amdgcn_mfma_f32_16x16x32_bf16(af, bfv, acc[cb], 0, 0, 0);
    }
  }
  #pragma unroll
  for (int cb = 0; cb < 8; cb++) {
    #pragma unroll
    for (int r = 0; r < 4; r++) {
      int node = row0 + lg * 4 + r;
      if (node < n_rows)
        out[(size_t)node * HD + cb * 16 + lr] = f2bf(lrelu(acc[cb][r]));
    }
  }
}

// ---------------- CSR build phase 1: bucket scatter ----------------
__global__ __launch_bounds__(256)
void bucket_scatter_kernel(const int* __restrict__ esrc, const int* __restrict__ edst,
                           int* __restrict__ gcnt, int2* __restrict__ ebuf, int nE) {
  __shared__ int cnt[256];
  __shared__ int cur[256];
  const int t = threadIdx.x;
  const int c0 = blockIdx.x * SCHUNK;
  int s_arr[16], d_arr[16];
  cnt[t] = 0;
  __syncthreads();
  #pragma unroll
  for (int k = 0; k < 16; k++) {
    int idx = c0 + k * 256 + t;
    if (idx < nE) {
      s_arr[k] = esrc[idx];
      int d = edst[idx];
      d_arr[k] = d;
      atomicAdd(&cnt[d >> 9], 1);
    } else d_arr[k] = -1;
  }
  __syncthreads();
  if (cnt[t] > 0) cur[t] = atomicAdd(&gcnt[t], cnt[t]);
  __syncthreads();
  #pragma unroll
  for (int k = 0; k < 16; k++) {
    if (d_arr[k] >= 0) {
      int b = d_arr[k] >> 9;
      int p = atomicAdd(&cur[b], 1);
      ebuf[(size_t)b * CAP + p] = make_int2(s_arr[k], d_arr[k]);
    }
  }
}

__device__ __forceinline__ int wave_incl_scan(int v) {
  int lane = threadIdx.x & 63;
  #pragma unroll
  for (int d = 1; d < 64; d <<= 1) {
    int tv = __shfl_up(v, d, 64);
    if (lane >= d) v += tv;
  }
  return v;
}

// ---------------- CSR build phase 2: per-bucket local build ----------------
__global__ __launch_bounds__(256)
void bucket_build_kernel(const int2* __restrict__ ebuf, const int* __restrict__ gcnt,
                         int* __restrict__ csr, int* __restrict__ offs,
                         int* __restrict__ deg, float* __restrict__ inv_deg, int n) {
  __shared__ int hist[512];
  __shared__ int offl[512];
  __shared__ int wsum[4];
  const int b = blockIdx.x, t = threadIdx.x;
  const int d0 = b << 9;
  const int cnt = gcnt[b];
  const size_t ebase = (size_t)b * CAP;
  hist[t] = 0; hist[t + 256] = 0;
  __syncthreads();
  for (int i = t; i < cnt; i += 256) {
    int2 e = ebuf[ebase + i];
    atomicAdd(&hist[e.y - d0], 1);
  }
  __syncthreads();
  int a0 = hist[2 * t], a1 = hist[2 * t + 1];
  int s = a0 + a1;
  int incl = wave_incl_scan(s);
  int wid = t >> 6;
  if ((t & 63) == 63) wsum[wid] = incl;
  __syncthreads();
  int wbase = 0;
  for (int w_ = 0; w_ < wid; w_++) wbase += wsum[w_];
  int excl = wbase + incl - s;
  offl[2 * t] = excl;
  offl[2 * t + 1] = excl + a0;
  __syncthreads();
  for (int i = t; i < 512; i += 256) {
    int g = d0 + i;
    if (g < n) {
      offs[g] = b * CAP + offl[i];
      int dg = hist[i];
      deg[g] = dg;
      inv_deg[g] = 1.0f / fmaxf((float)dg, 1.0f);
    }
  }
  __syncthreads();
  for (int i = t; i < cnt; i += 256) {
    int2 e = ebuf[ebase + i];
    int p = atomicAdd(&offl[e.y - d0], 1);
    csr[ebase + p] = e.x;
  }
}

// ---------------- mean aggregation: one wave per node ----------------
__global__ __launch_bounds__(256)
void agg_kernel(const unsigned short* __restrict__ x, const int* __restrict__ csr,
                const int* __restrict__ offs, const int* __restrict__ deg,
                const float* __restrict__ inv_deg, unsigned short* __restrict__ agg, int n) {
  int node = blockIdx.x * 4 + (threadIdx.x >> 6);
  if (node >= n) return;
  int l = threadIdx.x & 63;
  int sub = l >> 4, j = l & 15;
  int s0 = offs[node], d = deg[node];
  float acc0[8] = {0.f,0.f,0.f,0.f,0.f,0.f,0.f,0.f};
  float acc1[8] = {0.f,0.f,0.f,0.f,0.f,0.f,0.f,0.f};
  const unsigned short* xj = x + 8 * j;
  int i = sub;
  for (; i + 4 < d; i += 8) {
    int e0 = csr[s0 + i], e1 = csr[s0 + i + 4];
    ushort8 v0 = *(const ushort8*)(xj + (size_t)e0 * HD);
    ushort8 v1 = *(const ushort8*)(xj + (size_t)e1 * HD);
    #pragma unroll
    for (int q = 0; q < 8; q++) { acc0[q] += bf2f(v0[q]); acc1[q] += bf2f(v1[q]); }
  }
  if (i < d) {
    int e0 = csr[s0 + i];
    ushort8 v0 = *(const ushort8*)(xj + (size_t)e0 * HD);
    #pragma unroll
    for (int q = 0; q < 8; q++) acc0[q] += bf2f(v0[q]);
  }
  #pragma unroll
  for (int q = 0; q < 8; q++) {
    float a = acc0[q] + acc1[q];
    a += __shfl_xor(a, 16, 64);
    a += __shfl_xor(a, 32, 64);
    acc0[q] = a;
  }
  if (sub == 0) {
    float id = inv_deg[node];
    ushort8 o;
    #pragma unroll
    for (int q = 0; q < 8; q++) o[q] = f2bf(acc0[q] * id);
    *(ushort8*)(agg + (size_t)node * HD + 8 * j) = o;
  }
}

// ---------------- output layer: z = (x.wl, x.wr) then scalar aggregation ----------------
__global__ __launch_bounds__(256)
void zpass_kernel(const unsigned short* __restrict__ x, const float* __restrict__ Wl,
                  const float* __restrict__ Wr, float* __restrict__ zl,
                  float* __restrict__ zr, int n) {
  int node = blockIdx.x * 4 + (threadIdx.x >> 6);
  if (node >= n) return;
  int lane = threadIdx.x & 63;
  unsigned xv = *(const unsigned*)(x + (size_t)node * HD + 2 * lane);
  float x0 = bf2f((unsigned short)(xv & 0xffff));
  float x1 = bf2f((unsigned short)(xv >> 16));
  float2 wl = *(const float2*)(Wl + 2 * lane);
  float2 wr = *(const float2*)(Wr + 2 * lane);
  float sl = x0 * wl.x + x1 * wl.y;
  float sr = x0 * wr.x + x1 * wr.y;
  #pragma unroll
  for (int d = 32; d > 0; d >>= 1) {
    sl += __shfl_down(sl, d, 64);
    sr += __shfl_down(sr, d, 64);
  }
  if (lane == 0) { zl[node] = sl; zr[node] = sr; }
}

__global__ __launch_bounds__(256)
void zfinal_kernel(const float* __restrict__ zl, const float* __restrict__ zr,
                   const int* __restrict__ csr, const int* __restrict__ offs,
                   const int* __restrict__ deg, const float* __restrict__ inv_deg,
                   const float* __restrict__ bl, float* __restrict__ out, int n) {
  int i = blockIdx.x * 256 + threadIdx.x;
  if (i >= n) return;
  int s0 = offs[i], d = deg[i];
  float a = 0.f;
  #pragma unroll 4
  for (int e = 0; e < d; e++) a += zl[csr[s0 + e]];
  float s = a * inv_deg[i] + bl[0] + zr[i];
  out[i] = 1.0f / (1.0f + expf(-s));
}

extern "C" void kernel_launch(void* const* d_in, const int* in_sizes, int n_in,
                              void* d_out, int out_size, void* d_ws, size_t ws_size,
                              hipStream_t stream) {
  const float* x_gen  = (const float*)d_in[0];
  const float* x_load = (const float*)d_in[1];
  const float* x_or   = (const float*)d_in[2];
  const float* x_ex   = (const float*)d_in[3];
  const int*   edge   = (const int*)d_in[4];
  const int*   ptv    = (const int*)d_in[5];
  const float* Wg1  = (const float*)d_in[6],  *bg1  = (const float*)d_in[7];
  const float* Wg2  = (const float*)d_in[8],  *bg2  = (const float*)d_in[9];
  const float* Wld1 = (const float*)d_in[10], *bld1 = (const float*)d_in[11];
  const float* Wld2 = (const float*)d_in[12], *bld2 = (const float*)d_in[13];
  const float* Wor1 = (const float*)d_in[14], *bor1 = (const float*)d_in[15];
  const float* Wor2 = (const float*)d_in[16], *bor2 = (const float*)d_in[17];
  const float* Wex1 = (const float*)d_in[18], *bex1 = (const float*)d_in[19];
  const float* Wex2 = (const float*)d_in[20], *bex2 = (const float*)d_in[21];
  const float* Wl_h = (const float*)d_in[22], *bl_h = (const float*)d_in[23];
  const float* Wr_h = (const float*)d_in[24];
  const float* Wl_o = (const float*)d_in[25], *bl_o = (const float*)d_in[26];
  const float* Wr_o = (const float*)d_in[27];

  const int n_gen  = in_sizes[0] / 3;
  const int n_load = in_sizes[1] / 3;
  const int n_or   = in_sizes[2] / 6;
  const int n_ex   = in_sizes[3] / 6;
  const int nE     = in_sizes[4] / 2;
  const int N      = in_sizes[5];
  const int* esrc = edge;
  const int* edst = edge + nE;

  // padded segment geometry (each segment rounded to 64 rows)
  const int np0 = ((n_gen  + 63) / 64) * 64;
  const int np1 = ((n_load + 63) / 64) * 64;
  const int np2 = ((n_or   + 63) / 64) * 64;
  const int np3 = ((n_ex   + 63) / 64) * 64;
  const int NP  = np0 + np1 + np2 + np3;
  const int4 padCum    = make_int4(np0, np0 + np1, np0 + np1 + np2, NP);
  const int4 realStart = make_int4(0, n_gen, n_gen + n_load, n_gen + n_load + n_or);
  const int4 realCnt   = make_int4(n_gen, n_load, n_or, n_ex);

  const int NB = (N + NPB - 1) / NPB;   // buckets (<= 256 for N <= 131072)

  // ---- workspace layout ----
  size_t NPel = (size_t)NP * HD;
  size_t nel  = (size_t)N * HD;
  unsigned short* b0 = (unsigned short*)d_ws;  // h1 (padded) / later agg buffer
  unsigned short* b1 = b0 + NPel;              // x (real-indexed)
  unsigned short* b3 = b1 + nel;               // x next
  int*  gcnt = (int*)(b3 + nel);               // 256 ints
  int2* ebuf = (int2*)(gcnt + 256);            // NB*CAP edges
  int*  csr  = (int*)(ebuf + (size_t)NB * CAP);
  int*  offs = csr + (size_t)NB * CAP;
  int*  deg  = offs + N;
  float* inv_deg = (float*)(deg + N);
  float* zl = inv_deg + N;
  float* zr = zl + N;
  int*  invp = (int*)(zr + N);
  uintptr_t wp_addr = ((uintptr_t)(invp + N) + 15) & ~(uintptr_t)15;
  unsigned short* Wp = (unsigned short*)wp_addr;   // 4*16384 + 3*32768 bf16

  hipMemsetAsync(gcnt, 0, 256 * sizeof(int), stream);

  // ---- weight repack + inverse permutation ----
  wprep_all_kernel<<<640, 256, 0, stream>>>(Wg2, Wld2, Wor2, Wex2, Wl_h, Wr_h, Wp);
  invptv_kernel<<<(N + 255) / 256, 256, 0, stream>>>(ptv, invp, N);

  // ---- embeddings ----
  embed1_kernel<<<NP / 2, 256, 0, stream>>>(x_gen, x_load, x_or, x_ex,
                                            Wg1, bg1, Wld1, bld1, Wor1, bor1, Wex1, bex1,
                                            b0, padCum, realCnt);
  mfma_embed2_kernel<<<NP / 64, 256, 0, stream>>>(b0, Wp, bg2, bld2, bor2, bex2,
                                                  invp, b1, padCum, realStart, realCnt);

  // ---- CSR build (bucketed, LDS-local atomics) ----
  bucket_scatter_kernel<<<(nE + SCHUNK - 1) / SCHUNK, 256, 0, stream>>>(esrc, edst, gcnt, ebuf, nE);
  bucket_build_kernel<<<NB, 256, 0, stream>>>(ebuf, gcnt, csr, offs, deg, inv_deg, N);

  // ---- hidden SAGE layers ----
  unsigned short* xcur = b1;
  unsigned short* xnext = b3;
  const unsigned short* WpC = Wp + 4 * 16384;
  for (int l = 0; l < 3; l++) {
    agg_kernel<<<(N + 3) / 4, 256, 0, stream>>>(xcur, csr, offs, deg, inv_deg, b0, N);
    mfma_comb_kernel<<<(N + 63) / 64, 256, 0, stream>>>(b0, xcur, WpC + (size_t)l * 32768,
                                                        bl_h + (size_t)l * HD, xnext, N);
    unsigned short* tmp = xcur; xcur = xnext; xnext = tmp;
  }

  // ---- output layer via linearity: (A x)·wl = A (x·wl) ----
  zpass_kernel<<<(N + 3) / 4, 256, 0, stream>>>(xcur, Wl_o, Wr_o, zl, zr, N);
  zfinal_kernel<<<(N + 255) / 256, 256, 0, stream>>>(zl, zr, csr, offs, deg, inv_deg,
                                                     bl_o, (float*)d_out, N);
}